// Round 1
// 321.202 us; speedup vs baseline: 1.0713x; 1.0713x over previous
//
#include <hip/hip_runtime.h>

// Stream compaction, single-pass (R6):
//   mask[i]  = accept_index[i] >= 0
//   dst[i]   = exclusive_prefix_sum(mask)[i]
//   out[dst[i]] = out_cache_loc[accept_index[i]]  for mask[i]
//   out[total..N) = 0
//
// R5 post-mortem: scatter = 206us of 344us; the remaining ~138us is
// k_reduce (a redundant 64MB idx read), k_scan (single-block bubble),
// k_tail (16K-block sweep) and 3 launch gaps. R6 fuses everything into one
// pass:
//   - decoupled lookback (packed {flag,val} u64, agent-scope atomics)
//     replaces reduce+scan; aggregate published BEFORE the gather phase.
//   - tail zeroing fused via the reject-prefix identity: block b zeroes
//     [N - r_b - rejcnt_b, N - r_b) where r_b = b*TILE2 - base. These
//     ranges tile [total, N) exactly and never collide with data writes.
// Gather core (slice sweep, branch-free batched loads, one vmcnt(0) per
// slice, LDS compact, coalesced store) is unchanged from R5.

#define N_TOTAL  16777216
#define BLOCK    256

#define EPT2     32
#define TILE2    (BLOCK * EPT2)        // 8192
#define NB2      (N_TOTAL / TILE2)     // 2048

#define SLICE_LG 22                    // 2^22 elements = 16 MB per slice
#define SLICES   (N_TOTAL >> SLICE_LG) // 4

typedef float vfloat4 __attribute__((ext_vector_type(4)));

// ---------------- pass 0: zero the lookback state (16 KB) ----------------
__global__ __launch_bounds__(256) void k_init(unsigned long long* __restrict__ state) {
    state[blockIdx.x * 256 + threadIdx.x] = 0ULL;
}

// ---------------- single fused pass ----------------
__global__ __launch_bounds__(BLOCK) void k_compact(const int* __restrict__ idx,
                                                   const float* __restrict__ src,
                                                   float* __restrict__ out,
                                                   unsigned long long* __restrict__ state) {
    const int b = blockIdx.x;
    const int t = threadIdx.x;
    const int lane = t & 63, wave = t >> 6;

    // ---- load idx tile (only read of accept_index in the whole pipeline) ----
    const int4* p = (const int4*)(idx + (size_t)b * TILE2 + (size_t)t * EPT2);
    int v[EPT2];
#pragma unroll
    for (int j = 0; j < EPT2 / 4; ++j) {
        int4 q = p[j];
        v[4 * j + 0] = q.x; v[4 * j + 1] = q.y;
        v[4 * j + 2] = q.z; v[4 * j + 3] = q.w;
    }
    int cnt = 0;
#pragma unroll
    for (int j = 0; j < EPT2; ++j) cnt += (v[j] >= 0);

    // ---- block exclusive scan of per-thread counts ----
    int x = cnt;
#pragma unroll
    for (int d = 1; d < 64; d <<= 1) {
        int y = __shfl_up(x, d);
        if (lane >= d) x += y;
    }
    __shared__ int wsum[BLOCK / 64], woff[BLOCK / 64], btotal;
    __shared__ long long sBase;
    if (lane == 63) wsum[wave] = x;
    __syncthreads();
    if (t == 0) {
        int s = 0;
#pragma unroll
        for (int w = 0; w < BLOCK / 64; ++w) { woff[w] = s; s += wsum[w]; }
        btotal = s;
        if (b == 0) {
            // flag 2 = PREFIX (inclusive), value in bits [2..]
            __hip_atomic_store(&state[0], ((unsigned long long)s << 2) | 2ULL,
                               __ATOMIC_RELAXED, __HIP_MEMORY_SCOPE_AGENT);
            sBase = 0;
        } else {
            // flag 1 = PARTIAL (aggregate) -- published before the gather phase
            __hip_atomic_store(&state[b], ((unsigned long long)s << 2) | 1ULL,
                               __ATOMIC_RELAXED, __HIP_MEMORY_SCOPE_AGENT);
        }
    }

    // ---- decoupled lookback: wave 0, 64-wide windows ----
    if (b > 0 && wave == 0) {
        long long excl = 0;
        int look = b - 1;
        for (;;) {
            const int pos = look - lane;              // lane 0 = nearest predecessor
            unsigned long long s = 2ULL;              // pos<0 -> fake PREFIX(0)
            if (pos >= 0)
                s = __hip_atomic_load(&state[pos], __ATOMIC_RELAXED,
                                      __HIP_MEMORY_SCOPE_AGENT);
            for (;;) {
                const bool need = (pos >= 0) && ((s & 3ULL) == 0ULL);
                if (!__any(need)) break;
                if (need) {
                    __builtin_amdgcn_s_sleep(2);      // throttle spin traffic
                    s = __hip_atomic_load(&state[pos], __ATOMIC_RELAXED,
                                          __HIP_MEMORY_SCOPE_AGENT);
                }
            }
            const unsigned long long ball = __ballot((s & 3ULL) == 2ULL);
            const int fp = ball ? (__ffsll((long long)ball) - 1) : 64;
            long long c = (lane <= fp) ? (long long)(s >> 2) : 0; // fp==64 -> all
#pragma unroll
            for (int d = 32; d; d >>= 1) c += __shfl_down(c, d);
            excl += __shfl(c, 0);
            if (ball) break;                          // found a PREFIX -> done
            look -= 64;                               // whole window PARTIAL
        }
        if (lane == 0) {
            __hip_atomic_store(&state[b],
                               (((unsigned long long)(excl + btotal)) << 2) | 2ULL,
                               __ATOMIC_RELAXED, __HIP_MEMORY_SCOPE_AGENT);
            sBase = excl;
        }
    }
    __syncthreads();

    const int off0 = (x - cnt) + woff[wave];   // this thread's first LDS slot
    const int tot  = btotal;
    const long long base = sBase;              // global exclusive accept prefix

    // ---- slice-swept batched gather -> LDS compact (unchanged from R5) ----
    __shared__ float vals[TILE2];
#pragma unroll 1
    for (int s = 0; s < SLICES; ++s) {
        float tmp[EPT2];
#pragma unroll
        for (int j = 0; j < EPT2; ++j) {
            const bool m = (int)((unsigned)v[j] >> SLICE_LG) == s;
            tmp[j] = src[m ? v[j] : 0];
        }
        asm volatile("s_waitcnt vmcnt(0)" ::: "memory");
        int o = off0;
#pragma unroll
        for (int j = 0; j < EPT2; ++j) {
            const bool acc = v[j] >= 0;
            const bool m = (int)((unsigned)v[j] >> SLICE_LG) == s;
            if (m) vals[o] = tmp[j];
            o += acc;
        }
    }
    __syncthreads();

    // ---- contiguous, fully-coalesced block write: [base, base+tot) ----
    for (int i = t; i < tot; i += BLOCK)
        __builtin_nontemporal_store(vals[i], out + base + i);

    // ---- fused tail zero via reject-prefix identity ----
    // rejects before this block: r_b = b*TILE2 - base; this block owes
    // rcnt = TILE2 - tot zeros at [N - r_b - rcnt, N - r_b). Union over all
    // blocks = [total, N), disjoint, never overlaps data writes.
    const long long rprev = (long long)b * TILE2 - base;
    const int rcnt = TILE2 - tot;
    float* zp = out + ((long long)N_TOTAL - rprev - rcnt);
    for (int i = t; i < rcnt; i += BLOCK)
        __builtin_nontemporal_store(0.0f, zp + i);
}

extern "C" void kernel_launch(void* const* d_in, const int* in_sizes, int n_in,
                              void* d_out, int out_size, void* d_ws, size_t ws_size,
                              hipStream_t stream) {
    const int*   idx = (const int*)d_in[0];     // accept_index (int32 per harness)
    const float* src = (const float*)d_in[1];   // out_cache_loc
    float*       out = (float*)d_out;

    unsigned long long* state = (unsigned long long*)d_ws;  // NB2 x u64 = 16 KB

    k_init   <<<NB2 / 256, 256, 0, stream>>>(state);
    k_compact<<<NB2, BLOCK, 0, stream>>>(idx, src, out, state);
}